// Round 5
// baseline (286.390 us; speedup 1.0000x reference)
//
#include <hip/hip_runtime.h>

// B=4, C1=128, C2=64, H1=W1=128, H2=W2=256, G1=8, G2=16, BS1=8, BS2=16, nb=256.

// ---- workspace layout (float offsets) ----
#define GP1P_OFF 0        // [128 blocks][128 ch] x1 channel-sum partials
#define GP2P_OFF 16384    // [256 blocks][64 ch]  x2 channel-sum partials
#define P2_OFF   32768    // [64]  wsum[o]*kbn*gm[o]
#define P3_OFF   32832    // [64]  b_f[o]*kbn*gm[o] + bt[o]
#define WF2T_OFF 32896    // [4*64*64] BN-folded, transposed: [b][c][o]
#define POS1_OFF 49280    // [4*256*64]
#define POS2_OFF 114816   // [4*256*256]
#define SPA_OFF  376960   // [4*256*256]
// end 639104 floats = 2.44 MB

// ---------------- K1: fused single-pass gap-partials + pos convs ----------------
// blocks [0,128): x1 — 512 px/block (2 px/thread, float2), c-loop 128
// blocks [128,384): x2 — 1024 px/block (4 px/thread, float4), c-loop 64
// Each block touches 256KB exactly once (R4 k_gp read tensors twice, latency-bound 52us).
__global__ __launch_bounds__(256) void k_fuse(const float* __restrict__ x1,
                                              const float* __restrict__ x2,
                                              const float* __restrict__ w_p1,
                                              const float* __restrict__ b_p1,
                                              const float* __restrict__ w_p2,
                                              const float* __restrict__ b_p2,
                                              float* __restrict__ ws) {
  __shared__ float part[4][128];
  int blk = blockIdx.x, t = threadIdx.x;
  int wave = t >> 6, lane = t & 63;
  if (blk < 128) {
    int b = blk >> 5;
    int hw = ((blk << 9) + (t << 1)) & 16383;
    int h = hw >> 7, w0 = hw & 127;
    const float* p = x1 + ((size_t)b << 21) + hw;
    float bb = b_p1[0];
    float s0 = bb, s1 = 0.f;
#pragma unroll 8
    for (int c = 0; c < 128; ++c) {
      float2 v = *(const float2*)(p + ((size_t)c << 14));
      float wc = w_p1[c];
      s0 = fmaf(wc, v.x, s0);
      s1 = fmaf(wc, v.y, s1);
      float cs = v.x + v.y;
#pragma unroll
      for (int m = 32; m; m >>= 1) cs += __shfl_xor(cs, m);
      if (lane == 0) part[wave][c] = cs;
    }
    s1 += bb;
    int n = ((h >> 3) << 4) + (w0 >> 3);
    float2 o2; o2.x = s0; o2.y = s1;
    *(float2*)&ws[POS1_OFF + ((b * 256 + n) << 6) + ((h & 7) << 3) + (w0 & 7)] = o2;
    __syncthreads();
    if (t < 128)
      ws[GP1P_OFF + blk * 128 + t] =
          ((part[0][t] + part[1][t]) + (part[2][t] + part[3][t]));
  } else {
    int j = blk - 128;
    int b = j >> 6;
    int hw = ((j << 10) + (t << 2)) & 65535;
    int h = hw >> 8, w0 = hw & 255;
    const float* p = x2 + ((size_t)b << 22) + hw;
    float bb = b_p2[0];
    float s0 = bb, s1 = 0.f, s2 = 0.f, s3 = 0.f;
#pragma unroll 4
    for (int c = 0; c < 64; ++c) {
      float4 v = *(const float4*)(p + ((size_t)c << 16));
      float wc = w_p2[c];
      s0 = fmaf(wc, v.x, s0); s1 = fmaf(wc, v.y, s1);
      s2 = fmaf(wc, v.z, s2); s3 = fmaf(wc, v.w, s3);
      float cs = (v.x + v.y) + (v.z + v.w);
#pragma unroll
      for (int m = 32; m; m >>= 1) cs += __shfl_xor(cs, m);
      if (lane == 0) part[wave][c] = cs;
    }
    s1 += bb; s2 += bb; s3 += bb;
    int n = ((h >> 4) << 4) + (w0 >> 4);
    float4 o4; o4.x = s0; o4.y = s1; o4.z = s2; o4.w = s3;
    *(float4*)&ws[POS2_OFF + ((b * 256 + n) << 8) + ((h & 15) << 4) + (w0 & 15)] = o4;
    __syncthreads();
    if (t < 64)
      ws[GP2P_OFF + j * 64 + t] =
          ((part[0][t] + part[1][t]) + (part[2][t] + part[3][t]));
  }
}

// ---------------- K2: spatial attention (blocks 0..1023) + small-work block (1024) ----------------
__global__ __launch_bounds__(256) void k_attn(const float* __restrict__ w_lin,
                                              const float* __restrict__ b_lin,
                                              const float* __restrict__ w_c1,
                                              const float* __restrict__ b_c1,
                                              const float* __restrict__ w_c2,
                                              const float* __restrict__ b_c2,
                                              const float* __restrict__ w_f,
                                              const float* __restrict__ b_f,
                                              const float* __restrict__ gm,
                                              const float* __restrict__ bt,
                                              float* __restrict__ ws) {
  __shared__ float smem[1104];
  int t = threadIdx.x;
  const float kbn = 0.99999500003749969f;  // 1/sqrt(1+1e-5)
  if (blockIdx.x == 1024) {
    // ---- reduce gap partials, channel attention, BN-folded conv matrix ----
    float* g1s = smem;          // [512] = [b*128+ch]
    float* g2s = smem + 512;    // [256] = [b*64+ch]
    float* cw_s = smem + 768;   // [256]
    for (int idx = t; idx < 512; idx += 256) {
      int b = idx >> 7, ch = idx & 127;
      const float* gp = ws + GP1P_OFF + (b << 5) * 128 + ch;
      float s = 0.f;
#pragma unroll 8
      for (int i = 0; i < 32; ++i) s += gp[i * 128];
      g1s[idx] = s * (1.f / 16384.f);
    }
    {
      int b = t >> 6, ch = t & 63;
      const float* gp = ws + GP2P_OFF + (b << 6) * 64 + ch;
      float s = 0.f;
#pragma unroll 8
      for (int i = 0; i < 64; ++i) s += gp[i * 64];
      g2s[t] = s * (1.f / 65536.f);
    }
    __syncthreads();
    if (t < 32) {
      int b = t >> 3, g = t & 7;
      const float* g1 = g1s + b * 128 + g * 16;
      const float* g2 = g2s + b * 64 + g * 8;
      float m1[8], m2[8];
      for (int o = 0; o < 8; ++o) {
        float s = b_c1[o];
        for (int c = 0; c < 16; ++c) s = fmaf(w_c1[o * 16 + c], g1[c], s);
        m1[o] = fmaxf(s, 0.f);
      }
      float ss = 0.f;
      for (int p = 0; p < 8; ++p) {
        float s = b_c2[p];
        for (int c = 0; c < 8; ++c) s = fmaf(w_c2[p * 8 + c], g2[c], s);
        float r = fmaxf(s, 0.f);
        m2[p] = r; ss = fmaf(r, r, ss);
      }
      float lg[8], mx = -1e30f;
      for (int o = 0; o < 8; ++o) { lg[o] = m1[o] * ss; mx = fmaxf(mx, lg[o]); }
      float se = 0.f;
      for (int o = 0; o < 8; ++o) {
        lg[o] = __builtin_amdgcn_exp2f((lg[o] - mx) * 1.44269504088896f);
        se += lg[o];
      }
      float inv = 1.f / se;
      for (int o = 0; o < 8; ++o) cw_s[b * 64 + g * 8 + o] = lg[o] * inv;
    }
    __syncthreads();
    if (t < 64) {
      float s = 0.f;
      for (int c = 0; c < 64; ++c) s += w_f[t * 64 + c];
      float A = kbn * gm[t];
      ws[P2_OFF + t] = s * A;
      ws[P3_OFF + t] = fmaf(b_f[t], A, bt[t]);
    }
    for (int i = t; i < 16384; i += 256) {
      int b = i >> 12, rem = i & 4095;
      int c = rem >> 6, o = rem & 63;
      ws[WF2T_OFF + i] = w_f[o * 64 + c] * cw_s[b * 64 + c] * (kbn * gm[o]);
    }
    return;
  }
  // ---- rank-1 spatial attention for block bn ----
  float* P1 = smem;           // [64]
  float* V  = smem + 64;      // [256]
  float* A2 = smem + 320;     // [256]
  float* Sq = smem + 576;     // [256]
  float* Mq = smem + 832;     // [256]
  float* rmx = smem + 1088;   // [4]
  float* rmn = smem + 1092;   // [4]
  const float L2E = 1.44269504088896f;
  int bn = blockIdx.x;
  if (t < 64) P1[t] = ws[POS1_OFF + bn * 64 + t];
  float a = ws[POS2_OFF + bn * 256 + t];
  float a2 = a * L2E;
  A2[t] = a2;
  __syncthreads();
  float v = b_lin[t];
  const float* wr = w_lin + t * 64;
#pragma unroll 16
  for (int c = 0; c < 64; ++c) v = fmaf(wr[c], P1[c], v);
  V[t] = v;
  float vmax = v, vmin = v;
#pragma unroll
  for (int m = 32; m; m >>= 1) {
    vmax = fmaxf(vmax, __shfl_xor(vmax, m));
    vmin = fminf(vmin, __shfl_xor(vmin, m));
  }
  if ((t & 63) == 0) { rmx[t >> 6] = vmax; rmn[t >> 6] = vmin; }
  __syncthreads();
  vmax = fmaxf(fmaxf(rmx[0], rmx[1]), fmaxf(rmx[2], rmx[3]));
  vmin = fminf(fminf(rmn[0], rmn[1]), fminf(rmn[2], rmn[3]));
  float m2 = (a2 > 0.f) ? a2 * vmax : a2 * vmin;
  float d0 = 0.f, d1 = 0.f, d2 = 0.f, d3 = 0.f;
#pragma unroll 4
  for (int k = 0; k < 256; k += 4) {
    float4 vv = *(float4*)&V[k];
    d0 += __builtin_amdgcn_exp2f(fmaf(a2, vv.x, -m2));
    d1 += __builtin_amdgcn_exp2f(fmaf(a2, vv.y, -m2));
    d2 += __builtin_amdgcn_exp2f(fmaf(a2, vv.z, -m2));
    d3 += __builtin_amdgcn_exp2f(fmaf(a2, vv.w, -m2));
  }
  float den = (d0 + d1) + (d2 + d3);
  Sq[t] = a / den; Mq[t] = m2;
  __syncthreads();
  float c0 = 0.f, c1 = 0.f, c2 = 0.f, c3 = 0.f;
#pragma unroll 4
  for (int q = 0; q < 256; q += 4) {
    float4 aq = *(float4*)&A2[q];
    float4 sq = *(float4*)&Sq[q];
    float4 mq = *(float4*)&Mq[q];
    c0 = fmaf(sq.x, __builtin_amdgcn_exp2f(fmaf(aq.x, v, -mq.x)), c0);
    c1 = fmaf(sq.y, __builtin_amdgcn_exp2f(fmaf(aq.y, v, -mq.y)), c1);
    c2 = fmaf(sq.z, __builtin_amdgcn_exp2f(fmaf(aq.z, v, -mq.z)), c2);
    c3 = fmaf(sq.w, __builtin_amdgcn_exp2f(fmaf(aq.w, v, -mq.w)), c3);
  }
  ws[SPA_OFF + bn * 256 + t] = (c0 + c1) + (c2 + c3);
}

// ---------------- K3: fused 1x1 conv + BN + ReLU, 8o x (4+4)pix register tile ----------------
// Split-pixel mapping (pA, pA+128): LDS lane-stride 4 words -> 4-way conflict (1.58x)
// instead of R4's stride-8 (8-way, 2.94x per m136).
__global__ __launch_bounds__(256) void k_final(const float* __restrict__ x2,
                                               const float* __restrict__ ws,
                                               float* __restrict__ out) {
  __shared__ float Xt[64 * 256];   // [c][pix]
  __shared__ float Mt[64 * 64];    // [c][o], BN-folded
  int t = threadIdx.x;
  int blk = blockIdx.x;
  int b = blk >> 8;
  int p0 = (blk & 255) << 8;
  const float* xg = x2 + ((size_t)b << 22) + p0;
#pragma unroll
  for (int i = 0; i < 16; ++i) {
    int f4 = i * 256 + t;
    int c = f4 >> 6, col = (f4 & 63) << 2;
    float4 v = *(const float4*)(xg + ((size_t)c << 16) + col);
    *(float4*)&Xt[c * 256 + col] = v;
  }
  const float* mg = ws + WF2T_OFF + (b << 12);
#pragma unroll
  for (int i = 0; i < 4; ++i) {
    int f4 = i * 256 + t;
    *(float4*)&Mt[f4 << 2] = *(const float4*)(mg + ((size_t)f4 << 2));
  }
  __syncthreads();
  int og = (t >> 5) << 3;   // output-channel base
  int pA = (t & 31) << 2;   // first pixel-quad
  int pB = pA + 128;        // second pixel-quad
  float acc[8][8];
#pragma unroll
  for (int i = 0; i < 8; ++i)
#pragma unroll
    for (int j = 0; j < 8; ++j) acc[i][j] = 0.f;
#pragma unroll 4
  for (int c = 0; c < 64; ++c) {
    float4 xa = *(float4*)&Xt[c * 256 + pA];
    float4 xb = *(float4*)&Xt[c * 256 + pB];
    float4 ma = *(float4*)&Mt[(c << 6) + og];
    float4 mb = *(float4*)&Mt[(c << 6) + og + 4];
    float xs[8] = {xa.x, xa.y, xa.z, xa.w, xb.x, xb.y, xb.z, xb.w};
    float ms[8] = {ma.x, ma.y, ma.z, ma.w, mb.x, mb.y, mb.z, mb.w};
#pragma unroll
    for (int i = 0; i < 8; ++i)
#pragma unroll
      for (int j = 0; j < 8; ++j)
        acc[i][j] = fmaf(ms[i], xs[j], acc[i][j]);
  }
  const float* sp = ws + SPA_OFF + (b << 16) + p0;
  float4 sa = *(const float4*)(sp + pA);
  float4 sb = *(const float4*)(sp + pB);
  float spa[8] = {sa.x, sa.y, sa.z, sa.w, sb.x, sb.y, sb.z, sb.w};
  float* outp = out + ((size_t)b << 22) + p0;
#pragma unroll
  for (int i = 0; i < 8; ++i) {
    int o = og + i;
    float p2 = ws[P2_OFF + o];
    float p3 = ws[P3_OFF + o];
    float r[8];
#pragma unroll
    for (int j = 0; j < 8; ++j)
      r[j] = fmaxf(fmaf(spa[j], p2, acc[i][j] + p3), 0.f);
    float4 r0; r0.x = r[0]; r0.y = r[1]; r0.z = r[2]; r0.w = r[3];
    float4 r1; r1.x = r[4]; r1.y = r[5]; r1.z = r[6]; r1.w = r[7];
    float* po = outp + ((size_t)o << 16);
    *(float4*)(po + pA) = r0;
    *(float4*)(po + pB) = r1;
  }
}

extern "C" void kernel_launch(void* const* d_in, const int* in_sizes, int n_in,
                              void* d_out, int out_size, void* d_ws, size_t ws_size,
                              hipStream_t stream) {
  const float* x1   = (const float*)d_in[0];
  const float* x2   = (const float*)d_in[1];
  const float* w_c1 = (const float*)d_in[2];
  const float* b_c1 = (const float*)d_in[3];
  const float* w_c2 = (const float*)d_in[4];
  const float* b_c2 = (const float*)d_in[5];
  const float* w_p1 = (const float*)d_in[6];
  const float* b_p1 = (const float*)d_in[7];
  const float* w_p2 = (const float*)d_in[8];
  const float* b_p2 = (const float*)d_in[9];
  const float* w_lin= (const float*)d_in[10];
  const float* b_lin= (const float*)d_in[11];
  const float* w_f  = (const float*)d_in[12];
  const float* b_f  = (const float*)d_in[13];
  const float* gmm  = (const float*)d_in[14];
  const float* btt  = (const float*)d_in[15];
  float* ws  = (float*)d_ws;
  float* out = (float*)d_out;

  hipLaunchKernelGGL(k_fuse,  dim3(384),  dim3(256), 0, stream, x1, x2, w_p1, b_p1, w_p2, b_p2, ws);
  hipLaunchKernelGGL(k_attn,  dim3(1025), dim3(256), 0, stream, w_lin, b_lin,
                     w_c1, b_c1, w_c2, b_c2, w_f, b_f, gmm, btt, ws);
  hipLaunchKernelGGL(k_final, dim3(1024), dim3(256), 0, stream, x2, ws, out);
}

// Round 6
// 222.106 us; speedup vs baseline: 1.2894x; 1.2894x over previous
//
#include <hip/hip_runtime.h>

// B=4, C1=128, C2=64, H1=W1=128, H2=W2=256, G1=8, G2=16, BS1=8, BS2=16, nb=256.

// ---- workspace layout (float offsets) ----
#define GAP_OFF  0        // [768] atomic gap sums: [0,512)=x1 [b*128+c], [512,768)=x2 [b*64+c]
#define P2_OFF   768      // [64]  wsum[o]*kbn*gm[o]
#define P3_OFF   832      // [64]  b_f[o]*kbn*gm[o] + bt[o]
#define WF2T_OFF 896      // [4*64*64] BN-folded, transposed: [b][c][o]
#define POS1_OFF 17280    // [4*256*64]
#define POS2_OFF 82816    // [4*256*256]
#define SPA_OFF  344960   // [4*256*256]
// end 607104 floats = 2.32 MB

// ---------------- K1: single-pass gap+pos. NO cross-lane ops in the stream loop ----------------
// (R5 post-mortem: 6-deep shfl chain per c-iter = 768 serialized DS ops/thread -> 100us.
//  Now: per-lane register partials gs[i]; one LDS transpose at block end; atomic gap sums.)
// blocks [0,256): x1 — 256 px/block, wave w owns channels c==w (mod 4), 32 ch/wave
// blocks [256,1280): x2 — one row (256 px)/block, 16 ch/wave
__global__ __launch_bounds__(256) void k_fuse(const float* __restrict__ x1,
                                              const float* __restrict__ x2,
                                              const float* __restrict__ w_p1,
                                              const float* __restrict__ b_p1,
                                              const float* __restrict__ w_p2,
                                              const float* __restrict__ b_p2,
                                              float* __restrict__ ws) {
  __shared__ float gbuf[128 * 65];   // [row][lane], stride 65 kills read bank conflicts
  __shared__ float pbuf[1024];       // [wave][256 px] pos partials
  int blk = blockIdx.x, t = threadIdx.x;
  int wv = t >> 6, ln = t & 63;
  if (blk < 256) {
    int b = blk >> 6;
    int px0 = (blk & 63) << 8;
    const float* xb = x1 + ((size_t)b << 21) + px0 + (ln << 2);
    float4 pacc; pacc.x = pacc.y = pacc.z = pacc.w = 0.f;
    float gs[32];
#pragma unroll
    for (int i = 0; i < 32; ++i) {
      int c = (i << 2) + wv;
      float4 v = *(const float4*)(xb + ((size_t)c << 14));
      float wc = w_p1[c];
      pacc.x = fmaf(wc, v.x, pacc.x); pacc.y = fmaf(wc, v.y, pacc.y);
      pacc.z = fmaf(wc, v.z, pacc.z); pacc.w = fmaf(wc, v.w, pacc.w);
      gs[i] = (v.x + v.y) + (v.z + v.w);
    }
#pragma unroll
    for (int i = 0; i < 32; ++i) gbuf[((wv << 5) + i) * 65 + ln] = gs[i];
    *(float4*)&pbuf[(wv << 8) + (ln << 2)] = pacc;
    __syncthreads();
    if (t < 128) {
      // row t = (w2*32+i2); channel c = 4*i2 + w2
      int w2 = t >> 5, i2 = t & 31;
      int c = (i2 << 2) + w2;
      const float* gp = &gbuf[t * 65];
      float s0 = 0.f, s1 = 0.f, s2 = 0.f, s3 = 0.f;
#pragma unroll
      for (int k = 0; k < 64; k += 4) { s0 += gp[k]; s1 += gp[k+1]; s2 += gp[k+2]; s3 += gp[k+3]; }
      atomicAdd(&ws[GAP_OFF + b * 128 + c], (s0 + s1) + (s2 + s3));
    }
    float s = (pbuf[t] + pbuf[256 + t]) + (pbuf[512 + t] + pbuf[768 + t]) + b_p1[0];
    int p = px0 + t, h = p >> 7, w0 = p & 127;
    int n = ((h >> 3) << 4) + (w0 >> 3);
    ws[POS1_OFF + ((b * 256 + n) << 6) + ((h & 7) << 3) + (w0 & 7)] = s;
  } else {
    int j = blk - 256;
    int b = j >> 8;
    int row = j & 255;
    const float* xb = x2 + ((size_t)b << 22) + (row << 8) + (ln << 2);
    float4 pacc; pacc.x = pacc.y = pacc.z = pacc.w = 0.f;
    float gs[16];
#pragma unroll
    for (int i = 0; i < 16; ++i) {
      int c = (i << 2) + wv;
      float4 v = *(const float4*)(xb + ((size_t)c << 16));
      float wc = w_p2[c];
      pacc.x = fmaf(wc, v.x, pacc.x); pacc.y = fmaf(wc, v.y, pacc.y);
      pacc.z = fmaf(wc, v.z, pacc.z); pacc.w = fmaf(wc, v.w, pacc.w);
      gs[i] = (v.x + v.y) + (v.z + v.w);
    }
#pragma unroll
    for (int i = 0; i < 16; ++i) gbuf[((wv << 4) + i) * 65 + ln] = gs[i];
    *(float4*)&pbuf[(wv << 8) + (ln << 2)] = pacc;
    __syncthreads();
    if (t < 64) {
      int w2 = t >> 4, i2 = t & 15;
      int c = (i2 << 2) + w2;
      const float* gp = &gbuf[t * 65];
      float s0 = 0.f, s1 = 0.f, s2 = 0.f, s3 = 0.f;
#pragma unroll
      for (int k = 0; k < 64; k += 4) { s0 += gp[k]; s1 += gp[k+1]; s2 += gp[k+2]; s3 += gp[k+3]; }
      atomicAdd(&ws[GAP_OFF + 512 + b * 64 + c], (s0 + s1) + (s2 + s3));
    }
    float s = (pbuf[t] + pbuf[256 + t]) + (pbuf[512 + t] + pbuf[768 + t]) + b_p2[0];
    int n = ((row >> 4) << 4) + (t >> 4);
    ws[POS2_OFF + ((b * 256 + n) << 8) + ((row & 15) << 4) + (t & 15)] = s;
  }
}

// ---------------- K2: spatial attention (blocks 0..1023) + small-work block (1024) ----------------
__global__ __launch_bounds__(256) void k_attn(const float* __restrict__ w_lin,
                                              const float* __restrict__ b_lin,
                                              const float* __restrict__ w_c1,
                                              const float* __restrict__ b_c1,
                                              const float* __restrict__ w_c2,
                                              const float* __restrict__ b_c2,
                                              const float* __restrict__ w_f,
                                              const float* __restrict__ b_f,
                                              const float* __restrict__ gm,
                                              const float* __restrict__ bt,
                                              float* __restrict__ ws) {
  __shared__ float smem[1104];
  int t = threadIdx.x;
  const float kbn = 0.99999500003749969f;  // 1/sqrt(1+1e-5)
  if (blockIdx.x == 1024) {
    // ---- gap means from atomic sums, channel attention, BN-folded conv matrix ----
    float* g1s = smem;          // [512]
    float* g2s = smem + 512;    // [256]
    float* cw_s = smem + 768;   // [256]
    for (int idx = t; idx < 512; idx += 256) g1s[idx] = ws[GAP_OFF + idx] * (1.f / 16384.f);
    g2s[t] = ws[GAP_OFF + 512 + t] * (1.f / 65536.f);
    __syncthreads();
    if (t < 32) {
      int b = t >> 3, g = t & 7;
      const float* g1 = g1s + b * 128 + g * 16;
      const float* g2 = g2s + b * 64 + g * 8;
      float m1[8], m2[8];
      for (int o = 0; o < 8; ++o) {
        float s = b_c1[o];
        for (int c = 0; c < 16; ++c) s = fmaf(w_c1[o * 16 + c], g1[c], s);
        m1[o] = fmaxf(s, 0.f);
      }
      float ss = 0.f;
      for (int p = 0; p < 8; ++p) {
        float s = b_c2[p];
        for (int c = 0; c < 8; ++c) s = fmaf(w_c2[p * 8 + c], g2[c], s);
        float r = fmaxf(s, 0.f);
        m2[p] = r; ss = fmaf(r, r, ss);
      }
      float lg[8], mx = -1e30f;
      for (int o = 0; o < 8; ++o) { lg[o] = m1[o] * ss; mx = fmaxf(mx, lg[o]); }
      float se = 0.f;
      for (int o = 0; o < 8; ++o) {
        lg[o] = __builtin_amdgcn_exp2f((lg[o] - mx) * 1.44269504088896f);
        se += lg[o];
      }
      float inv = 1.f / se;
      for (int o = 0; o < 8; ++o) cw_s[b * 64 + g * 8 + o] = lg[o] * inv;
    }
    __syncthreads();
    if (t < 64) {
      float s = 0.f;
      for (int c = 0; c < 64; ++c) s += w_f[t * 64 + c];
      float A = kbn * gm[t];
      ws[P2_OFF + t] = s * A;
      ws[P3_OFF + t] = fmaf(b_f[t], A, bt[t]);
    }
    for (int i = t; i < 16384; i += 256) {
      int b = i >> 12, rem = i & 4095;
      int c = rem >> 6, o = rem & 63;
      ws[WF2T_OFF + i] = w_f[o * 64 + c] * cw_s[b * 64 + c] * (kbn * gm[o]);
    }
    return;
  }
  // ---- rank-1 spatial attention; 2^(-m) folded into row scale T (drops Mq array) ----
  float* P1 = smem;           // [64]
  float* V  = smem + 64;      // [256]
  float* A2 = smem + 320;     // [256]
  float* T  = smem + 576;     // [256]
  float* rmx = smem + 832;    // [4]
  float* rmn = smem + 836;    // [4]
  const float L2E = 1.44269504088896f;
  int bn = blockIdx.x;
  if (t < 64) P1[t] = ws[POS1_OFF + bn * 64 + t];
  float a = ws[POS2_OFF + bn * 256 + t];
  float a2 = a * L2E;
  A2[t] = a2;
  __syncthreads();
  float v = b_lin[t];
  const float* wr = w_lin + t * 64;
#pragma unroll 16
  for (int c = 0; c < 64; ++c) v = fmaf(wr[c], P1[c], v);
  V[t] = v;
  float vmax = v, vmin = v;
#pragma unroll
  for (int m = 32; m; m >>= 1) {
    vmax = fmaxf(vmax, __shfl_xor(vmax, m));
    vmin = fminf(vmin, __shfl_xor(vmin, m));
  }
  if ((t & 63) == 0) { rmx[t >> 6] = vmax; rmn[t >> 6] = vmin; }
  __syncthreads();
  vmax = fmaxf(fmaxf(rmx[0], rmx[1]), fmaxf(rmx[2], rmx[3]));
  vmin = fminf(fminf(rmn[0], rmn[1]), fminf(rmn[2], rmn[3]));
  float m2 = (a2 > 0.f) ? a2 * vmax : a2 * vmin;
  float d0 = 0.f, d1 = 0.f, d2 = 0.f, d3 = 0.f;
#pragma unroll 4
  for (int k = 0; k < 256; k += 4) {
    float4 vv = *(float4*)&V[k];
    d0 += __builtin_amdgcn_exp2f(fmaf(a2, vv.x, -m2));
    d1 += __builtin_amdgcn_exp2f(fmaf(a2, vv.y, -m2));
    d2 += __builtin_amdgcn_exp2f(fmaf(a2, vv.z, -m2));
    d3 += __builtin_amdgcn_exp2f(fmaf(a2, vv.w, -m2));
  }
  float den = (d0 + d1) + (d2 + d3);
  T[t] = (a / den) * __builtin_amdgcn_exp2f(-m2);
  __syncthreads();
  float c0 = 0.f, c1 = 0.f, c2 = 0.f, c3 = 0.f;
#pragma unroll 4
  for (int q = 0; q < 256; q += 4) {
    float4 aq = *(float4*)&A2[q];
    float4 tq = *(float4*)&T[q];
    c0 = fmaf(tq.x, __builtin_amdgcn_exp2f(aq.x * v), c0);
    c1 = fmaf(tq.y, __builtin_amdgcn_exp2f(aq.y * v), c1);
    c2 = fmaf(tq.z, __builtin_amdgcn_exp2f(aq.z * v), c2);
    c3 = fmaf(tq.w, __builtin_amdgcn_exp2f(aq.w * v), c3);
  }
  ws[SPA_OFF + bn * 256 + t] = (c0 + c1) + (c2 + c3);
}

// ---------------- K3: fused 1x1 conv + BN + ReLU, 8o x (4+4)pix register tile ----------------
__global__ __launch_bounds__(256) void k_final(const float* __restrict__ x2,
                                               const float* __restrict__ ws,
                                               float* __restrict__ out) {
  __shared__ float Xt[64 * 256];   // [c][pix]
  __shared__ float Mt[64 * 64];    // [c][o], BN-folded
  int t = threadIdx.x;
  int blk = blockIdx.x;
  int b = blk >> 8;
  int p0 = (blk & 255) << 8;
  const float* xg = x2 + ((size_t)b << 22) + p0;
#pragma unroll
  for (int i = 0; i < 16; ++i) {
    int f4 = i * 256 + t;
    int c = f4 >> 6, col = (f4 & 63) << 2;
    float4 v = *(const float4*)(xg + ((size_t)c << 16) + col);
    *(float4*)&Xt[c * 256 + col] = v;
  }
  const float* mg = ws + WF2T_OFF + (b << 12);
#pragma unroll
  for (int i = 0; i < 4; ++i) {
    int f4 = i * 256 + t;
    *(float4*)&Mt[f4 << 2] = *(const float4*)(mg + ((size_t)f4 << 2));
  }
  __syncthreads();
  int og = (t >> 5) << 3;
  int pA = (t & 31) << 2;
  int pB = pA + 128;
  float acc[8][8];
#pragma unroll
  for (int i = 0; i < 8; ++i)
#pragma unroll
    for (int j = 0; j < 8; ++j) acc[i][j] = 0.f;
#pragma unroll 4
  for (int c = 0; c < 64; ++c) {
    float4 xa = *(float4*)&Xt[c * 256 + pA];
    float4 xb = *(float4*)&Xt[c * 256 + pB];
    float4 ma = *(float4*)&Mt[(c << 6) + og];
    float4 mb = *(float4*)&Mt[(c << 6) + og + 4];
    float xs[8] = {xa.x, xa.y, xa.z, xa.w, xb.x, xb.y, xb.z, xb.w};
    float ms[8] = {ma.x, ma.y, ma.z, ma.w, mb.x, mb.y, mb.z, mb.w};
#pragma unroll
    for (int i = 0; i < 8; ++i)
#pragma unroll
      for (int j = 0; j < 8; ++j)
        acc[i][j] = fmaf(ms[i], xs[j], acc[i][j]);
  }
  const float* sp = ws + SPA_OFF + (b << 16) + p0;
  float4 sa = *(const float4*)(sp + pA);
  float4 sb = *(const float4*)(sp + pB);
  float spa[8] = {sa.x, sa.y, sa.z, sa.w, sb.x, sb.y, sb.z, sb.w};
  float* outp = out + ((size_t)b << 22) + p0;
#pragma unroll
  for (int i = 0; i < 8; ++i) {
    int o = og + i;
    float p2 = ws[P2_OFF + o];
    float p3 = ws[P3_OFF + o];
    float r[8];
#pragma unroll
    for (int j = 0; j < 8; ++j)
      r[j] = fmaxf(fmaf(spa[j], p2, acc[i][j] + p3), 0.f);
    float4 r0; r0.x = r[0]; r0.y = r[1]; r0.z = r[2]; r0.w = r[3];
    float4 r1; r1.x = r[4]; r1.y = r[5]; r1.z = r[6]; r1.w = r[7];
    float* po = outp + ((size_t)o << 16);
    *(float4*)(po + pA) = r0;
    *(float4*)(po + pB) = r1;
  }
}

extern "C" void kernel_launch(void* const* d_in, const int* in_sizes, int n_in,
                              void* d_out, int out_size, void* d_ws, size_t ws_size,
                              hipStream_t stream) {
  const float* x1   = (const float*)d_in[0];
  const float* x2   = (const float*)d_in[1];
  const float* w_c1 = (const float*)d_in[2];
  const float* b_c1 = (const float*)d_in[3];
  const float* w_c2 = (const float*)d_in[4];
  const float* b_c2 = (const float*)d_in[5];
  const float* w_p1 = (const float*)d_in[6];
  const float* b_p1 = (const float*)d_in[7];
  const float* w_p2 = (const float*)d_in[8];
  const float* b_p2 = (const float*)d_in[9];
  const float* w_lin= (const float*)d_in[10];
  const float* b_lin= (const float*)d_in[11];
  const float* w_f  = (const float*)d_in[12];
  const float* b_f  = (const float*)d_in[13];
  const float* gmm  = (const float*)d_in[14];
  const float* btt  = (const float*)d_in[15];
  float* ws  = (float*)d_ws;
  float* out = (float*)d_out;

  // zero the atomic gap-sum region (ws is re-poisoned 0xAA before every launch)
  hipMemsetAsync(ws, 0, 768 * sizeof(float), stream);
  hipLaunchKernelGGL(k_fuse,  dim3(1280), dim3(256), 0, stream, x1, x2, w_p1, b_p1, w_p2, b_p2, ws);
  hipLaunchKernelGGL(k_attn,  dim3(1025), dim3(256), 0, stream, w_lin, b_lin,
                     w_c1, b_c1, w_c2, b_c2, w_f, b_f, gmm, btt, ws);
  hipLaunchKernelGGL(k_final, dim3(1024), dim3(256), 0, stream, x2, ws, out);
}

// Round 7
// 221.996 us; speedup vs baseline: 1.2901x; 1.0005x over previous
//
#include <hip/hip_runtime.h>

// B=4, C1=128, C2=64, H1=W1=128, H2=W2=256, G1=8, G2=16, BS1=8, BS2=16, nb=256.

// ---- workspace layout (float offsets) ----
#define GAP_OFF  0        // [768] atomic gap sums: [0,512)=x1 [b*128+c], [512,768)=x2 [b*64+c]
#define POS1_OFF 768      // [4*256*64]
#define POS2_OFF 66304    // [4*256*256]
// end 328448 floats = 1.25 MB

// ---------------- K1: single-pass gap+pos (unchanged from R6: register partials, ----------------
// one LDS transpose per block, atomic gap sums; no cross-lane ops in the stream loop)
__global__ __launch_bounds__(256) void k_fuse(const float* __restrict__ x1,
                                              const float* __restrict__ x2,
                                              const float* __restrict__ w_p1,
                                              const float* __restrict__ b_p1,
                                              const float* __restrict__ w_p2,
                                              const float* __restrict__ b_p2,
                                              float* __restrict__ ws) {
  __shared__ float gbuf[128 * 65];   // [row][lane], stride 65 kills bank conflicts
  __shared__ float pbuf[1024];       // [wave][256 px] pos partials
  int blk = blockIdx.x, t = threadIdx.x;
  int wv = t >> 6, ln = t & 63;
  if (blk < 256) {
    int b = blk >> 6;
    int px0 = (blk & 63) << 8;
    const float* xb = x1 + ((size_t)b << 21) + px0 + (ln << 2);
    float4 pacc; pacc.x = pacc.y = pacc.z = pacc.w = 0.f;
    float gs[32];
#pragma unroll
    for (int i = 0; i < 32; ++i) {
      int c = (i << 2) + wv;
      float4 v = *(const float4*)(xb + ((size_t)c << 14));
      float wc = w_p1[c];
      pacc.x = fmaf(wc, v.x, pacc.x); pacc.y = fmaf(wc, v.y, pacc.y);
      pacc.z = fmaf(wc, v.z, pacc.z); pacc.w = fmaf(wc, v.w, pacc.w);
      gs[i] = (v.x + v.y) + (v.z + v.w);
    }
#pragma unroll
    for (int i = 0; i < 32; ++i) gbuf[((wv << 5) + i) * 65 + ln] = gs[i];
    *(float4*)&pbuf[(wv << 8) + (ln << 2)] = pacc;
    __syncthreads();
    if (t < 128) {
      int w2 = t >> 5, i2 = t & 31;
      int c = (i2 << 2) + w2;
      const float* gp = &gbuf[t * 65];
      float s0 = 0.f, s1 = 0.f, s2 = 0.f, s3 = 0.f;
#pragma unroll
      for (int k = 0; k < 64; k += 4) { s0 += gp[k]; s1 += gp[k+1]; s2 += gp[k+2]; s3 += gp[k+3]; }
      atomicAdd(&ws[GAP_OFF + b * 128 + c], (s0 + s1) + (s2 + s3));
    }
    float s = (pbuf[t] + pbuf[256 + t]) + (pbuf[512 + t] + pbuf[768 + t]) + b_p1[0];
    int p = px0 + t, h = p >> 7, w0 = p & 127;
    int n = ((h >> 3) << 4) + (w0 >> 3);
    ws[POS1_OFF + ((b * 256 + n) << 6) + ((h & 7) << 3) + (w0 & 7)] = s;
  } else {
    int j = blk - 256;
    int b = j >> 8;
    int row = j & 255;
    const float* xb = x2 + ((size_t)b << 22) + (row << 8) + (ln << 2);
    float4 pacc; pacc.x = pacc.y = pacc.z = pacc.w = 0.f;
    float gs[16];
#pragma unroll
    for (int i = 0; i < 16; ++i) {
      int c = (i << 2) + wv;
      float4 v = *(const float4*)(xb + ((size_t)c << 16));
      float wc = w_p2[c];
      pacc.x = fmaf(wc, v.x, pacc.x); pacc.y = fmaf(wc, v.y, pacc.y);
      pacc.z = fmaf(wc, v.z, pacc.z); pacc.w = fmaf(wc, v.w, pacc.w);
      gs[i] = (v.x + v.y) + (v.z + v.w);
    }
#pragma unroll
    for (int i = 0; i < 16; ++i) gbuf[((wv << 4) + i) * 65 + ln] = gs[i];
    *(float4*)&pbuf[(wv << 8) + (ln << 2)] = pacc;
    __syncthreads();
    if (t < 64) {
      int w2 = t >> 4, i2 = t & 15;
      int c = (i2 << 2) + w2;
      const float* gp = &gbuf[t * 65];
      float s0 = 0.f, s1 = 0.f, s2 = 0.f, s3 = 0.f;
#pragma unroll
      for (int k = 0; k < 64; k += 4) { s0 += gp[k]; s1 += gp[k+1]; s2 += gp[k+2]; s3 += gp[k+3]; }
      atomicAdd(&ws[GAP_OFF + 512 + b * 64 + c], (s0 + s1) + (s2 + s3));
    }
    float s = (pbuf[t] + pbuf[256 + t]) + (pbuf[512 + t] + pbuf[768 + t]) + b_p2[0];
    int n = ((row >> 4) << 4) + (t >> 4);
    ws[POS2_OFF + ((b * 256 + n) << 8) + ((row & 15) << 4) + (t & 15)] = s;
  }
}

// ---------------- K2: merged attention + channel-attn weights + conv+BN+ReLU ----------------
// Block bn=(b,n) computes the rank-1 attention for row n (exactly the 256 SPA values
// its conv needs), redundantly computes cw / M (tiny), then does the 64x64 conv for
// row n streaming X from global (no Xt LDS staging -> LDS pipe load halved vs R6,
// 22KB LDS -> 4+ blocks/CU vs 2).
__global__ __launch_bounds__(256) void k_mrg(const float* __restrict__ x2,
                                             const float* __restrict__ w_lin,
                                             const float* __restrict__ b_lin,
                                             const float* __restrict__ w_c1,
                                             const float* __restrict__ b_c1,
                                             const float* __restrict__ w_c2,
                                             const float* __restrict__ b_c2,
                                             const float* __restrict__ w_f,
                                             const float* __restrict__ b_f,
                                             const float* __restrict__ gm,
                                             const float* __restrict__ bt,
                                             const float* __restrict__ ws,
                                             float* __restrict__ out) {
  __shared__ float Mt[4096];                 // [c][o], BN+cw folded
  __shared__ float P1[64], V[256], A2[256], T[256], spa_s[256];
  __shared__ float g1s[128], g2s[64], cw_l[64], p2s[64], p3s[64];
  __shared__ float rmx[4], rmn[4];
  const float L2E = 1.44269504088896f;
  const float kbn = 0.99999500003749969f;    // 1/sqrt(1+1e-5)
  int t = threadIdx.x;
  int blk = blockIdx.x;
  int b = blk >> 8, n = blk & 255;

  // S0: loads
  if (t < 128) g1s[t] = ws[GAP_OFF + b * 128 + t] * (1.f / 16384.f);
  if (t < 64)  g2s[t] = ws[GAP_OFF + 512 + b * 64 + t] * (1.f / 65536.f);
  if (t < 64)  P1[t] = ws[POS1_OFF + blk * 64 + t];
  float a = ws[POS2_OFF + blk * 256 + t];
  float a2 = a * L2E;
  A2[t] = a2;
  __syncthreads();

  // S1: x1t row + wave max/min; threads 0..7 also run the tiny channel-attn MLP
  float v = b_lin[t];
  const float* wr = w_lin + t * 64;
#pragma unroll 16
  for (int c = 0; c < 64; ++c) v = fmaf(wr[c], P1[c], v);
  V[t] = v;
  float vmax = v, vmin = v;
#pragma unroll
  for (int m = 32; m; m >>= 1) {
    vmax = fmaxf(vmax, __shfl_xor(vmax, m));
    vmin = fminf(vmin, __shfl_xor(vmin, m));
  }
  if ((t & 63) == 0) { rmx[t >> 6] = vmax; rmn[t >> 6] = vmin; }
  if (t < 8) {
    int g = t;
    const float* g1 = g1s + g * 16;
    const float* g2 = g2s + g * 8;
    float m1[8];
    for (int o = 0; o < 8; ++o) {
      float s = b_c1[o];
      for (int c = 0; c < 16; ++c) s = fmaf(w_c1[o * 16 + c], g1[c], s);
      m1[o] = fmaxf(s, 0.f);
    }
    float ss = 0.f;
    for (int p = 0; p < 8; ++p) {
      float s = b_c2[p];
      for (int c = 0; c < 8; ++c) s = fmaf(w_c2[p * 8 + c], g2[c], s);
      float r = fmaxf(s, 0.f);
      ss = fmaf(r, r, ss);
    }
    float lg[8], mx = -1e30f;
    for (int o = 0; o < 8; ++o) { lg[o] = m1[o] * ss; mx = fmaxf(mx, lg[o]); }
    float se = 0.f;
    for (int o = 0; o < 8; ++o) {
      lg[o] = __builtin_amdgcn_exp2f((lg[o] - mx) * L2E);
      se += lg[o];
    }
    float inv = 1.f / se;
    for (int o = 0; o < 8; ++o) cw_l[g * 8 + o] = lg[o] * inv;
  }
  __syncthreads();

  // S2: softmax denominator (rank-1: rowmax from vmax/vmin); threads 0..63 also fold P2/P3
  vmax = fmaxf(fmaxf(rmx[0], rmx[1]), fmaxf(rmx[2], rmx[3]));
  vmin = fminf(fminf(rmn[0], rmn[1]), fminf(rmn[2], rmn[3]));
  float m2 = (a2 > 0.f) ? a2 * vmax : a2 * vmin;
  float d0 = 0.f, d1 = 0.f, d2 = 0.f, d3 = 0.f;
#pragma unroll 4
  for (int k = 0; k < 256; k += 4) {
    float4 vv = *(float4*)&V[k];
    d0 += __builtin_amdgcn_exp2f(fmaf(a2, vv.x, -m2));
    d1 += __builtin_amdgcn_exp2f(fmaf(a2, vv.y, -m2));
    d2 += __builtin_amdgcn_exp2f(fmaf(a2, vv.z, -m2));
    d3 += __builtin_amdgcn_exp2f(fmaf(a2, vv.w, -m2));
  }
  float den = (d0 + d1) + (d2 + d3);
  T[t] = (a / den) * __builtin_amdgcn_exp2f(-m2);
  if (t < 64) {
    const float4* wrow = (const float4*)(w_f + t * 64);
    float s0 = 0.f, s1 = 0.f, s2 = 0.f, s3 = 0.f;
#pragma unroll
    for (int k = 0; k < 16; ++k) {
      float4 wv = wrow[k];
      s0 += wv.x; s1 += wv.y; s2 += wv.z; s3 += wv.w;
    }
    float A = kbn * gm[t];
    p2s[t] = ((s0 + s1) + (s2 + s3)) * A;
    p3s[t] = fmaf(b_f[t], A, bt[t]);
  }
  __syncthreads();

  // S3: attention pass 2 (spa row) + Mt build (overlaps exp-heavy pass with global reads)
  float c0 = 0.f, c1 = 0.f, c2 = 0.f, c3 = 0.f;
#pragma unroll 4
  for (int q = 0; q < 256; q += 4) {
    float4 aq = *(float4*)&A2[q];
    float4 tq = *(float4*)&T[q];
    c0 = fmaf(tq.x, __builtin_amdgcn_exp2f(aq.x * v), c0);
    c1 = fmaf(tq.y, __builtin_amdgcn_exp2f(aq.y * v), c1);
    c2 = fmaf(tq.z, __builtin_amdgcn_exp2f(aq.z * v), c2);
    c3 = fmaf(tq.w, __builtin_amdgcn_exp2f(aq.w * v), c3);
  }
  spa_s[t] = (c0 + c1) + (c2 + c3);
#pragma unroll
  for (int i = 0; i < 16; ++i) {
    int idx = i * 256 + t;            // = c*64 + o
    int c = idx >> 6, o = idx & 63;
    Mt[idx] = w_f[o * 64 + c] * cw_l[c] * (kbn * gm[o]);
  }
  __syncthreads();

  // S4: conv for row n — X streamed from global (L1-hot), M from LDS (broadcast)
  int og = (t >> 5) << 3;
  int pA = (t & 31) << 2;
  int pB = pA + 128;
  const float* xg = x2 + ((size_t)b << 22) + (n << 8);
  float acc[8][8];
#pragma unroll
  for (int i = 0; i < 8; ++i)
#pragma unroll
    for (int j = 0; j < 8; ++j) acc[i][j] = 0.f;
#pragma unroll 4
  for (int c = 0; c < 64; ++c) {
    float4 xa = *(const float4*)(xg + ((size_t)c << 16) + pA);
    float4 xb = *(const float4*)(xg + ((size_t)c << 16) + pB);
    float4 ma = *(float4*)&Mt[(c << 6) + og];
    float4 mb = *(float4*)&Mt[(c << 6) + og + 4];
    float xs[8] = {xa.x, xa.y, xa.z, xa.w, xb.x, xb.y, xb.z, xb.w};
    float ms[8] = {ma.x, ma.y, ma.z, ma.w, mb.x, mb.y, mb.z, mb.w};
#pragma unroll
    for (int i = 0; i < 8; ++i)
#pragma unroll
      for (int j = 0; j < 8; ++j)
        acc[i][j] = fmaf(ms[i], xs[j], acc[i][j]);
  }
  float spa[8];
#pragma unroll
  for (int j = 0; j < 4; ++j) { spa[j] = spa_s[pA + j]; spa[4 + j] = spa_s[pB + j]; }
  float* outp = out + ((size_t)b << 22) + (n << 8);
#pragma unroll
  for (int i = 0; i < 8; ++i) {
    int o = og + i;
    float p2 = p2s[o];
    float p3 = p3s[o];
    float r[8];
#pragma unroll
    for (int j = 0; j < 8; ++j)
      r[j] = fmaxf(fmaf(spa[j], p2, acc[i][j] + p3), 0.f);
    float4 r0; r0.x = r[0]; r0.y = r[1]; r0.z = r[2]; r0.w = r[3];
    float4 r1; r1.x = r[4]; r1.y = r[5]; r1.z = r[6]; r1.w = r[7];
    float* po = outp + ((size_t)o << 16);
    *(float4*)(po + pA) = r0;
    *(float4*)(po + pB) = r1;
  }
}

extern "C" void kernel_launch(void* const* d_in, const int* in_sizes, int n_in,
                              void* d_out, int out_size, void* d_ws, size_t ws_size,
                              hipStream_t stream) {
  const float* x1   = (const float*)d_in[0];
  const float* x2   = (const float*)d_in[1];
  const float* w_c1 = (const float*)d_in[2];
  const float* b_c1 = (const float*)d_in[3];
  const float* w_c2 = (const float*)d_in[4];
  const float* b_c2 = (const float*)d_in[5];
  const float* w_p1 = (const float*)d_in[6];
  const float* b_p1 = (const float*)d_in[7];
  const float* w_p2 = (const float*)d_in[8];
  const float* b_p2 = (const float*)d_in[9];
  const float* w_lin= (const float*)d_in[10];
  const float* b_lin= (const float*)d_in[11];
  const float* w_f  = (const float*)d_in[12];
  const float* b_f  = (const float*)d_in[13];
  const float* gmm  = (const float*)d_in[14];
  const float* btt  = (const float*)d_in[15];
  float* ws  = (float*)d_ws;
  float* out = (float*)d_out;

  // zero the atomic gap-sum region (ws is re-poisoned 0xAA before every launch)
  hipMemsetAsync(ws, 0, 768 * sizeof(float), stream);
  hipLaunchKernelGGL(k_fuse, dim3(1280), dim3(256), 0, stream, x1, x2, w_p1, b_p1, w_p2, b_p2, ws);
  hipLaunchKernelGGL(k_mrg,  dim3(1024), dim3(256), 0, stream, x2, w_lin, b_lin,
                     w_c1, b_c1, w_c2, b_c2, w_f, b_f, gmm, btt, ws, out);
}